// Round 3
// baseline (1077.713 us; speedup 1.0000x reference)
//
#include <hip/hip_runtime.h>
#include <math.h>

#define IN_DIM_C 128
#define OUT_DIM_C 64
#define T_STEPS 8
#define KC_MAX 512          // max coarse buckets (N/256 = 391 actual)
#define TILE 4096
#define VT 16               // edges per thread per tile (256 * 16 = 4096)

__device__ __forceinline__ float4 f4zero() { return make_float4(0.f, 0.f, 0.f, 0.f); }

// ---------------- degree: indegree via atomics (400 KB target, L2/L3-resident) -----------
__global__ __launch_bounds__(256) void k_deg(const int* __restrict__ dst,
                                             int* __restrict__ deg, int E) {
    int e = blockIdx.x * 256 + threadIdx.x;
    if (e < E) atomicAdd(&deg[dst[e]], 1);
}

// ---------------- GEMM: h = x @ W  (fp32 vector ALU) ----------------
__global__ __launch_bounds__(256) void k_gemm(const float* __restrict__ x,
                                              const float* __restrict__ W,
                                              float* __restrict__ h,
                                              int n, int n_groups) {
    __shared__ __align__(16) float Ws[IN_DIM_C * OUT_DIM_C];   // 32 KB, [k][d]
    __shared__ __align__(16) float xs[16 * 136];               // 16 rows, padded stride 136

    for (int i = threadIdx.x; i < IN_DIM_C * OUT_DIM_C / 4; i += 256)
        ((float4*)Ws)[i] = ((const float4*)W)[i];

    const int ln = threadIdx.x >> 4;
    const int dg = threadIdx.x & 15;
    const float4* Ws4 = (const float4*)Ws;

    for (int g = blockIdx.x; g < n_groups; g += gridDim.x) {
        int node_base = g * 16;
        __syncthreads();
        for (int f = threadIdx.x; f < 512; f += 256) {
            int row = f >> 5, c4 = f & 31;
            int node = node_base + row;
            float4 v = f4zero();
            if (node < n) v = *(const float4*)&x[(long)node * IN_DIM_C + c4 * 4];
            *(float4*)&xs[row * 136 + c4 * 4] = v;
        }
        __syncthreads();

        int node = node_base + ln;
        float4 acc = f4zero();
        #pragma unroll
        for (int k = 0; k < IN_DIM_C; k += 4) {
            float4 xv = *(const float4*)&xs[ln * 136 + k];
            float4 w0 = Ws4[(k + 0) * 16 + dg];
            float4 w1 = Ws4[(k + 1) * 16 + dg];
            float4 w2 = Ws4[(k + 2) * 16 + dg];
            float4 w3 = Ws4[(k + 3) * 16 + dg];
            acc.x = fmaf(xv.x, w0.x, acc.x); acc.y = fmaf(xv.x, w0.y, acc.y);
            acc.z = fmaf(xv.x, w0.z, acc.z); acc.w = fmaf(xv.x, w0.w, acc.w);
            acc.x = fmaf(xv.y, w1.x, acc.x); acc.y = fmaf(xv.y, w1.y, acc.y);
            acc.z = fmaf(xv.y, w1.z, acc.z); acc.w = fmaf(xv.y, w1.w, acc.w);
            acc.x = fmaf(xv.z, w2.x, acc.x); acc.y = fmaf(xv.z, w2.y, acc.y);
            acc.z = fmaf(xv.z, w2.z, acc.z); acc.w = fmaf(xv.z, w2.w, acc.w);
            acc.x = fmaf(xv.w, w3.x, acc.x); acc.y = fmaf(xv.w, w3.y, acc.y);
            acc.z = fmaf(xv.w, w3.z, acc.z); acc.w = fmaf(xv.w, w3.w, acc.w);
        }
        if (node < n)
            *(float4*)&h[(long)node * OUT_DIM_C + dg * 4] = acc;
    }
}

// ---------------- per-bucket degree sums + dinv (one block per 256-node bucket) ----------
__global__ __launch_bounds__(256) void k_bsum(const int* __restrict__ deg,
                                              int* __restrict__ chist,
                                              float* __restrict__ dinv, int n) {
    __shared__ int ws[4];
    int node = (blockIdx.x << 8) + threadIdx.x;
    int d = (node < n) ? deg[node] : 0;
    if (node < n) dinv[node] = rsqrtf((float)(d + 1));
    int s = d;
    #pragma unroll
    for (int off = 1; off < 64; off <<= 1) s += __shfl_xor(s, off, 64);
    if ((threadIdx.x & 63) == 0) ws[threadIdx.x >> 6] = s;
    __syncthreads();
    if (threadIdx.x == 0) chist[blockIdx.x] = ws[0] + ws[1] + ws[2] + ws[3];
}

// ---------------- tiny scan: exclusive prefix over kc bucket counts -> gcursor -----------
__global__ __launch_bounds__(64) void k_scanK(const int* __restrict__ chist,
                                              int* __restrict__ gcursor, int kc) {
    int lane = threadIdx.x;
    int carry = 0;
    for (int c = 0; c * 64 < kc; ++c) {
        int idx = c * 64 + lane;
        int v = (idx < kc) ? chist[idx] : 0;
        int x = v;
        #pragma unroll
        for (int off = 1; off < 64; off <<= 1) {
            int t = __shfl_up(x, off, 64);
            if (lane >= off) x += t;
        }
        if (idx < kc) gcursor[idx] = carry + x - v;
        carry += __shfl(x, 63, 64);
    }
}

// ---------------- partition: edges -> coarse buckets (combined writes via LDS stage) -----
// packed = (src << 8) | (dst & 255); bucket = dst >> 8
__global__ __launch_bounds__(256) void k_part(const int* __restrict__ src,
                                              const int* __restrict__ dst,
                                              int* __restrict__ gcursor,
                                              int* __restrict__ part,
                                              int E, int ntiles, int kc) {
    __shared__ int hist[KC_MAX];
    __shared__ int offs[KC_MAX];    // exclusive offsets, INF-padded for binary search
    __shared__ int gbase[KC_MAX];
    __shared__ int staged[TILE];
    __shared__ int s_total;
    const int tid = threadIdx.x;

    for (int tile = blockIdx.x; tile < ntiles; tile += gridDim.x) {
        for (int i = tid; i < KC_MAX; i += 256) { hist[i] = 0; offs[i] = 0x7fffffff; }
        __syncthreads();

        long base = (long)tile * TILE;
        int pk[VT], bk[VT], rk[VT];
        #pragma unroll
        for (int k = 0; k < VT; ++k) {
            long e = base + tid + k * 256;
            if (e < E) {
                int s = src[e], d = dst[e];
                pk[k] = (s << 8) | (d & 255);
                bk[k] = d >> 8;
                rk[k] = atomicAdd(&hist[bk[k]], 1);
            } else bk[k] = -1;
        }
        __syncthreads();

        // exclusive scan of hist (wave 0 only)
        if (tid < 64) {
            int carry = 0;
            for (int c = 0; c * 64 < kc; ++c) {
                int idx = c * 64 + tid;
                int v = (idx < kc) ? hist[idx] : 0;
                int x = v;
                #pragma unroll
                for (int off = 1; off < 64; off <<= 1) {
                    int t = __shfl_up(x, off, 64);
                    if (tid >= off) x += t;
                }
                if (idx < kc) offs[idx] = carry + x - v;
                carry += __shfl(x, 63, 64);
            }
            if (tid == 0) s_total = carry;
        }
        __syncthreads();

        // place into staged (bucket-grouped) + reserve global ranges
        #pragma unroll
        for (int k = 0; k < VT; ++k)
            if (bk[k] >= 0) staged[offs[bk[k]] + rk[k]] = pk[k];
        for (int b2 = tid; b2 < kc; b2 += 256)
            if (hist[b2] > 0) gbase[b2] = atomicAdd(&gcursor[b2], hist[b2]);
        __syncthreads();

        // write out: per-bucket contiguous runs
        int total = s_total;
        for (int idx = tid; idx < total; idx += 256) {
            int bb = 0;   // largest b with offs[b] <= idx (offs[0] == 0)
            #pragma unroll
            for (int step = 256; step; step >>= 1)
                if (bb + step < KC_MAX && offs[bb + step] <= idx) bb += step;
            part[gbase[bb] + idx - offs[bb]] = staged[idx];
        }
        __syncthreads();
    }
}

// ---------------- accumulate: one block per bucket, LDS agg, coalesced writeout ----------
__global__ __launch_bounds__(512) void k_accum(const int* __restrict__ part,
                                               const int* __restrict__ gcursor,
                                               const float* __restrict__ dinv,
                                               const float* __restrict__ h,
                                               const float* __restrict__ bias,
                                               float* __restrict__ agg, int n) {
    __shared__ float sagg[256 * 64];   // 64 KB
    const int tid = threadIdx.x;
    const int bkt = blockIdx.x;
    const int lane = tid & 63;
    const int wv = tid >> 6;           // 0..7

    for (int i = tid; i < 256 * 64 / 4; i += 512) ((float4*)sagg)[i] = f4zero();
    __syncthreads();

    int start = bkt ? gcursor[bkt - 1] : 0;   // post-partition: gcursor[b] == end(b)
    int end = gcursor[bkt];
    int node_base = bkt << 8;

    for (int i0 = start + wv * 8; i0 < end; i0 += 64) {
        int m = end - i0; if (m > 8) m = 8;
        int p[8]; float v[8];
        #pragma unroll
        for (int k = 0; k < 8; ++k) if (k < m) p[k] = part[i0 + k];
        #pragma unroll
        for (int k = 0; k < 8; ++k) if (k < m) {
            int s = p[k] >> 8;
            float nrm = dinv[s] * dinv[node_base + (p[k] & 255)];
            v[k] = nrm * h[(long)s * OUT_DIM_C + lane];
        }
        #pragma unroll
        for (int k = 0; k < 8; ++k) if (k < m)
            atomicAdd(&sagg[(p[k] & 255) * 64 + lane], v[k]);
    }
    __syncthreads();

    // epilogue: self-loop + bias, coalesced store
    for (int el = tid; el < 256 * 64; el += 512) {
        int node = node_base + (el >> 6);
        if (node >= n) break;          // node monotone in el for fixed tid
        int dim = el & 63;
        float dd = dinv[node];
        float val = sagg[el] + dd * dd * h[(long)node * OUT_DIM_C + dim] + bias[dim];
        agg[(long)node * OUT_DIM_C + dim] = val;
    }
}

// ---------------- spiking recurrence: 16 lanes/node; cached origin-step fast path ---------
__global__ __launch_bounds__(256) void k_spike(const float* agg,
                                               float* o_seq, float* z_seq, int n) {
    int gid = blockIdx.x * 256 + threadIdx.x;
    int node = gid >> 4;
    int sub = threadIdx.x & 15;
    if (node >= n) return;
    const float s0 = (sub == 0) ? -1.0f : 1.0f;
    int lane0 = (threadIdx.x & 63) & ~15;

    float4 g = *(const float4*)&agg[(long)node * OUT_DIM_C + sub * 4];
    float4 origin = f4zero();
    if (sub == 0) origin.x = 1.0f;

    auto step = [&](float4 z, float4& zn, bool& sp) {
        float p = s0 * z.x * g.x + z.y * g.y + z.z * g.z + z.w * g.w;
        p += __shfl_xor(p, 1, 64);
        p += __shfl_xor(p, 2, 64);
        p += __shfl_xor(p, 4, 64);
        p += __shfl_xor(p, 8, 64);
        float4 u = make_float4(fmaf(p, z.x, g.x), fmaf(p, z.y, g.y),
                               fmaf(p, z.z, g.z), fmaf(p, z.w, g.w));
        float q = s0 * u.x * u.x + u.y * u.y + u.z * u.z + u.w * u.w;
        q += __shfl_xor(q, 1, 64);
        q += __shfl_xor(q, 2, 64);
        q += __shfl_xor(q, 4, 64);
        q += __shfl_xor(q, 8, 64);
        float un = sqrtf(fmaxf(q, 1e-7f));
        float c = coshf(un);
        float sh = sinhf(un) / un;
        zn = make_float4(fmaf(c, z.x, sh * u.x), fmaf(c, z.y, sh * u.y),
                         fmaf(c, z.z, sh * u.z), fmaf(c, z.w, sh * u.w));
        float z0 = __shfl(zn.x, lane0, 64);
        float v = acoshf(fmaxf(z0, 1.0f + 1e-7f));
        sp = (v >= 1.0f);
    };

    float4 z1; bool sp0;
    step(origin, z1, sp0);
    float4 r0 = sp0 ? origin : z1;

    float4 z = origin;
    bool at0 = true;
    for (int t = 0; t < T_STEPS; ++t) {
        float4 zn; bool sp;
        if (at0) { sp = sp0; zn = r0; }
        else {
            step(z, zn, sp);
            if (sp) zn = origin;
        }
        *(float4*)&z_seq[(long)t * n * OUT_DIM_C + (long)node * OUT_DIM_C + sub * 4] = zn;
        if (sub == 0) o_seq[(long)t * n + node] = sp ? 1.0f : 0.0f;
        z = zn;
        at0 = sp;
    }
}

extern "C" void kernel_launch(void* const* d_in, const int* in_sizes, int n_in,
                              void* d_out, int out_size, void* d_ws, size_t ws_size,
                              hipStream_t stream) {
    const float* x  = (const float*)d_in[0];
    const int*   ei = (const int*)d_in[1];
    const float* W  = (const float*)d_in[2];
    const float* b  = (const float*)d_in[3];
    const int N = in_sizes[0] / IN_DIM_C;   // 100000
    const int E = in_sizes[1] / 2;          // 1600000
    const int KC = (N + 255) >> 8;          // 391 coarse buckets

    float* out   = (float*)d_out;
    float* o_seq = out;                              // [T, N]
    float* z_seq = out + (long)T_STEPS * N;          // [T, N, 64]

    // scratch aliased into z_seq slabs (each fully consumed before k_spike overwrites):
    float* agg     = z_seq;                                   // slab 0
    float* h       = z_seq + 1L * N * OUT_DIM_C;              // slab 1
    int*   part    = (int*)(z_seq + 2L * N * OUT_DIM_C);      // slab 2: E ints (6.4 MB)
    int*   deg     = (int*)(z_seq + 3L * N * OUT_DIM_C);      // slab 3: N ints
    int*   chist   = deg + N;                                 // KC ints
    int*   gcursor = chist + KC;                              // KC ints
    float* dinv    = (float*)(gcursor + KC);                  // N floats

    const int* srcp = ei;
    const int* dstp = ei + E;

    hipMemsetAsync(deg, 0, (size_t)(N + KC) * sizeof(int), stream);   // deg + chist
    k_deg<<<(E + 255) / 256, 256, 0, stream>>>(dstp, deg, E);

    int n_groups = (N + 15) / 16;
    k_gemm<<<1024, 256, 0, stream>>>(x, W, h, N, n_groups);

    k_bsum<<<KC, 256, 0, stream>>>(deg, chist, dinv, N);
    k_scanK<<<1, 64, 0, stream>>>(chist, gcursor, KC);

    int ntiles = (E + TILE - 1) / TILE;
    k_part<<<ntiles, 256, 0, stream>>>(srcp, dstp, gcursor, part, E, ntiles, KC);
    k_accum<<<KC, 512, 0, stream>>>(part, gcursor, dinv, h, b, agg, N);

    k_spike<<<(N + 15) / 16, 256, 0, stream>>>(agg, o_seq, z_seq, N);
}

// Round 4
// 433.350 us; speedup vs baseline: 2.4869x; 2.4869x over previous
//
#include <hip/hip_runtime.h>
#include <math.h>

#define IN_DIM_C 128
#define OUT_DIM_C 64
#define T_STEPS 8
#define KC_MAX 512          // max coarse buckets (N/256 = 391 actual)
#define PTILE 2048          // edges per k_part block

__device__ __forceinline__ float4 f4zero() { return make_float4(0.f, 0.f, 0.f, 0.f); }

// ---------------- coarse histogram: per-block LDS hist -> global atomics -----------------
__global__ __launch_bounds__(256) void k_hist(const int* __restrict__ dst,
                                              int* __restrict__ chist, int E) {
    __shared__ int hh[KC_MAX];
    const int tid = threadIdx.x;
    for (int i = tid; i < KC_MAX; i += 256) hh[i] = 0;
    __syncthreads();
    long base = (long)blockIdx.x * 4096;
    #pragma unroll
    for (int j = 0; j < 16; ++j) {
        long e = base + j * 256 + tid;
        if (e < E) atomicAdd(&hh[dst[e] >> 8], 1);
    }
    __syncthreads();
    for (int i = tid; i < KC_MAX; i += 256)
        if (hh[i]) atomicAdd(&chist[i], hh[i]);
}

// ---------------- tiny scan: exclusive prefix over kc bucket counts -> gcursor -----------
__global__ __launch_bounds__(64) void k_scanK(const int* __restrict__ chist,
                                              int* __restrict__ gcursor,
                                              int* __restrict__ offsets,
                                              int kc, int n, int E) {
    int lane = threadIdx.x;
    int carry = 0;
    for (int c = 0; c * 64 < kc; ++c) {
        int idx = c * 64 + lane;
        int v = (idx < kc) ? chist[idx] : 0;
        int x = v;
        #pragma unroll
        for (int off = 1; off < 64; off <<= 1) {
            int t = __shfl_up(x, off, 64);
            if (lane >= off) x += t;
        }
        if (idx < kc) gcursor[idx] = carry + x - v;
        carry += __shfl(x, 63, 64);
    }
    if (lane == 0) offsets[n] = E;
}

// ---------------- GEMM: h = x @ W  (fp32 vector ALU) ----------------
__global__ __launch_bounds__(256) void k_gemm(const float* __restrict__ x,
                                              const float* __restrict__ W,
                                              float* __restrict__ h,
                                              int n, int n_groups) {
    __shared__ __align__(16) float Ws[IN_DIM_C * OUT_DIM_C];   // 32 KB, [k][d]
    __shared__ __align__(16) float xs[16 * 136];               // 16 rows, padded stride 136

    for (int i = threadIdx.x; i < IN_DIM_C * OUT_DIM_C / 4; i += 256)
        ((float4*)Ws)[i] = ((const float4*)W)[i];

    const int ln = threadIdx.x >> 4;
    const int dg = threadIdx.x & 15;
    const float4* Ws4 = (const float4*)Ws;

    for (int g = blockIdx.x; g < n_groups; g += gridDim.x) {
        int node_base = g * 16;
        __syncthreads();
        for (int f = threadIdx.x; f < 512; f += 256) {
            int row = f >> 5, c4 = f & 31;
            int node = node_base + row;
            float4 v = f4zero();
            if (node < n) v = *(const float4*)&x[(long)node * IN_DIM_C + c4 * 4];
            *(float4*)&xs[row * 136 + c4 * 4] = v;
        }
        __syncthreads();

        int node = node_base + ln;
        float4 acc = f4zero();
        #pragma unroll
        for (int k = 0; k < IN_DIM_C; k += 4) {
            float4 xv = *(const float4*)&xs[ln * 136 + k];
            float4 w0 = Ws4[(k + 0) * 16 + dg];
            float4 w1 = Ws4[(k + 1) * 16 + dg];
            float4 w2 = Ws4[(k + 2) * 16 + dg];
            float4 w3 = Ws4[(k + 3) * 16 + dg];
            acc.x = fmaf(xv.x, w0.x, acc.x); acc.y = fmaf(xv.x, w0.y, acc.y);
            acc.z = fmaf(xv.x, w0.z, acc.z); acc.w = fmaf(xv.x, w0.w, acc.w);
            acc.x = fmaf(xv.y, w1.x, acc.x); acc.y = fmaf(xv.y, w1.y, acc.y);
            acc.z = fmaf(xv.y, w1.z, acc.z); acc.w = fmaf(xv.y, w1.w, acc.w);
            acc.x = fmaf(xv.z, w2.x, acc.x); acc.y = fmaf(xv.z, w2.y, acc.y);
            acc.z = fmaf(xv.z, w2.z, acc.z); acc.w = fmaf(xv.z, w2.w, acc.w);
            acc.x = fmaf(xv.w, w3.x, acc.x); acc.y = fmaf(xv.w, w3.y, acc.y);
            acc.z = fmaf(xv.w, w3.z, acc.z); acc.w = fmaf(xv.w, w3.w, acc.w);
        }
        if (node < n)
            *(float4*)&h[(long)node * OUT_DIM_C + dg * 4] = acc;
    }
}

// ---------------- coarse partition: direct scattered stores into per-bucket runs ---------
// packed = (src << 8) | (dst & 255); bucket = dst >> 8. Only 391 concurrent write
// windows -> all combining happens in L2; net write ~= 6.4 MB.
__global__ __launch_bounds__(256) void k_part(const int* __restrict__ src,
                                              const int* __restrict__ dst,
                                              int* __restrict__ gcursor,
                                              int* __restrict__ part, int E, int kc) {
    __shared__ int hist[KC_MAX];
    __shared__ int offs[KC_MAX];
    __shared__ int cur[KC_MAX];
    __shared__ int gbase[KC_MAX];
    const int tid = threadIdx.x;
    long base = (long)blockIdx.x * PTILE;

    for (int i = tid; i < KC_MAX; i += 256) hist[i] = 0;
    __syncthreads();
    #pragma unroll
    for (int j = 0; j < PTILE / 256; ++j) {
        long e = base + j * 256 + tid;
        if (e < E) atomicAdd(&hist[dst[e] >> 8], 1);
    }
    __syncthreads();
    // exclusive scan of hist (wave 0)
    if (tid < 64) {
        int carry = 0;
        for (int c = 0; c * 64 < kc; ++c) {
            int idx = c * 64 + tid;
            int v = (idx < kc) ? hist[idx] : 0;
            int x = v;
            #pragma unroll
            for (int off = 1; off < 64; off <<= 1) {
                int t = __shfl_up(x, off, 64);
                if (tid >= off) x += t;
            }
            if (idx < kc) { offs[idx] = carry + x - v; cur[idx] = carry + x - v; }
            carry += __shfl(x, 63, 64);
        }
    }
    __syncthreads();
    for (int b = tid; b < kc; b += 256)
        gbase[b] = hist[b] ? atomicAdd(&gcursor[b], hist[b]) : 0;
    __syncthreads();
    #pragma unroll
    for (int j = 0; j < PTILE / 256; ++j) {
        long e = base + j * 256 + tid;
        if (e < E) {
            int d = dst[e];
            int b = d >> 8;
            int r = atomicAdd(&cur[b], 1);
            part[gbase[b] + r - offs[b]] = (src[e] << 8) | (d & 255);
        }
    }
}

// ---------------- fine sort within bucket: counting sort in a 16 KB window ---------------
// Also produces per-node CSR offsets and dinv (degrees from counting pass).
__global__ __launch_bounds__(256) void k_sort(const int* __restrict__ part,
                                              const int* __restrict__ gcursor,
                                              int* __restrict__ part2,
                                              int* __restrict__ offsets,
                                              float* __restrict__ dinv, int n) {
    __shared__ int cnt[256];
    __shared__ int cur[256];
    __shared__ int wsum[4], woff[4];
    const int tid = threadIdx.x;
    const int bkt = blockIdx.x;
    int start = bkt ? gcursor[bkt - 1] : 0;   // post-partition: gcursor[b] == end(b)
    int end = gcursor[bkt];

    cnt[tid] = 0;
    __syncthreads();
    for (int i = start + tid; i < end; i += 256)
        atomicAdd(&cnt[part[i] & 255], 1);
    __syncthreads();

    // exclusive scan of cnt[256] (4 waves + cross-wave fixup)
    int v = cnt[tid];
    int lane = tid & 63, wv = tid >> 6;
    int x = v;
    #pragma unroll
    for (int off = 1; off < 64; off <<= 1) {
        int t = __shfl_up(x, off, 64);
        if (lane >= off) x += t;
    }
    if (lane == 63) wsum[wv] = x;
    __syncthreads();
    if (tid == 0) { int c = 0; for (int w = 0; w < 4; ++w) { woff[w] = c; c += wsum[w]; } }
    __syncthreads();
    int myloc = woff[wv] + x - v;            // exclusive local offset
    cur[tid] = myloc;
    int node = (bkt << 8) + tid;
    if (node < n) {
        offsets[node] = start + myloc;
        dinv[node] = rsqrtf((float)(v + 1));
    }
    __syncthreads();

    for (int i = start + tid; i < end; i += 256) {
        int p = part[i];
        int r = atomicAdd(&cur[p & 255], 1);
        part2[start + r] = ((unsigned)p) >> 8;   // src node id
    }
}

// ---------------- pull aggregation: one wave per dst node, lane = dim ---------------------
__global__ __launch_bounds__(256) void k_pull(const int* __restrict__ offsets,
                                              const int* __restrict__ part2,
                                              const float* __restrict__ dinv,
                                              const float* __restrict__ h,
                                              const float* __restrict__ b,
                                              float* __restrict__ agg, int n) {
    int node = (blockIdx.x * 256 + threadIdx.x) >> 6;
    int lane = threadIdx.x & 63;
    if (node >= n) return;
    int o0 = offsets[node], o1 = offsets[node + 1];
    float dd = dinv[node];
    float acc = fmaf(dd * dd, h[(long)node * OUT_DIM_C + lane], b[lane]);
    int i = o0;
    for (; i + 4 <= o1; i += 4) {
        int s0 = part2[i], s1 = part2[i + 1], s2 = part2[i + 2], s3 = part2[i + 3];
        float n0 = dinv[s0] * dd, n1 = dinv[s1] * dd, n2 = dinv[s2] * dd, n3 = dinv[s3] * dd;
        acc = fmaf(n0, h[(long)s0 * OUT_DIM_C + lane], acc);
        acc = fmaf(n1, h[(long)s1 * OUT_DIM_C + lane], acc);
        acc = fmaf(n2, h[(long)s2 * OUT_DIM_C + lane], acc);
        acc = fmaf(n3, h[(long)s3 * OUT_DIM_C + lane], acc);
    }
    for (; i < o1; ++i) {
        int s = part2[i];
        acc = fmaf(dinv[s] * dd, h[(long)s * OUT_DIM_C + lane], acc);
    }
    agg[(long)node * OUT_DIM_C + lane] = acc;
}

// ---------------- spiking recurrence: 16 lanes/node; cached origin-step fast path ---------
__global__ __launch_bounds__(256) void k_spike(const float* agg,
                                               float* o_seq, float* z_seq, int n) {
    int gid = blockIdx.x * 256 + threadIdx.x;
    int node = gid >> 4;
    int sub = threadIdx.x & 15;
    if (node >= n) return;
    const float s0 = (sub == 0) ? -1.0f : 1.0f;
    int lane0 = (threadIdx.x & 63) & ~15;

    float4 g = *(const float4*)&agg[(long)node * OUT_DIM_C + sub * 4];
    float4 origin = f4zero();
    if (sub == 0) origin.x = 1.0f;

    auto step = [&](float4 z, float4& zn, bool& sp) {
        float p = s0 * z.x * g.x + z.y * g.y + z.z * g.z + z.w * g.w;
        p += __shfl_xor(p, 1, 64);
        p += __shfl_xor(p, 2, 64);
        p += __shfl_xor(p, 4, 64);
        p += __shfl_xor(p, 8, 64);
        float4 u = make_float4(fmaf(p, z.x, g.x), fmaf(p, z.y, g.y),
                               fmaf(p, z.z, g.z), fmaf(p, z.w, g.w));
        float q = s0 * u.x * u.x + u.y * u.y + u.z * u.z + u.w * u.w;
        q += __shfl_xor(q, 1, 64);
        q += __shfl_xor(q, 2, 64);
        q += __shfl_xor(q, 4, 64);
        q += __shfl_xor(q, 8, 64);
        float un = sqrtf(fmaxf(q, 1e-7f));
        float c = coshf(un);
        float sh = sinhf(un) / un;
        zn = make_float4(fmaf(c, z.x, sh * u.x), fmaf(c, z.y, sh * u.y),
                         fmaf(c, z.z, sh * u.z), fmaf(c, z.w, sh * u.w));
        float z0 = __shfl(zn.x, lane0, 64);
        float v = acoshf(fmaxf(z0, 1.0f + 1e-7f));
        sp = (v >= 1.0f);
    };

    float4 z1; bool sp0;
    step(origin, z1, sp0);
    float4 r0 = sp0 ? origin : z1;

    float4 z = origin;
    bool at0 = true;
    for (int t = 0; t < T_STEPS; ++t) {
        float4 zn; bool sp;
        if (at0) { sp = sp0; zn = r0; }
        else {
            step(z, zn, sp);
            if (sp) zn = origin;
        }
        *(float4*)&z_seq[(long)t * n * OUT_DIM_C + (long)node * OUT_DIM_C + sub * 4] = zn;
        if (sub == 0) o_seq[(long)t * n + node] = sp ? 1.0f : 0.0f;
        z = zn;
        at0 = sp;
    }
}

extern "C" void kernel_launch(void* const* d_in, const int* in_sizes, int n_in,
                              void* d_out, int out_size, void* d_ws, size_t ws_size,
                              hipStream_t stream) {
    const float* x  = (const float*)d_in[0];
    const int*   ei = (const int*)d_in[1];
    const float* W  = (const float*)d_in[2];
    const float* b  = (const float*)d_in[3];
    const int N = in_sizes[0] / IN_DIM_C;   // 100000
    const int E = in_sizes[1] / 2;          // 1600000
    const int KC = (N + 255) >> 8;          // 391 coarse buckets

    float* out   = (float*)d_out;
    float* o_seq = out;                              // [T, N]
    float* z_seq = out + (long)T_STEPS * N;          // [T, N, 64]

    // scratch aliased into z_seq slabs (each fully consumed before k_spike overwrites):
    float* agg     = z_seq;                                   // slab 0
    float* h       = z_seq + 1L * N * OUT_DIM_C;              // slab 1
    int*   part    = (int*)(z_seq + 2L * N * OUT_DIM_C);      // slab 2: E ints
    int*   part2   = (int*)(z_seq + 3L * N * OUT_DIM_C);      // slab 3: E ints
    int*   chist   = (int*)(z_seq + 4L * N * OUT_DIM_C);      // slab 4: KC ints
    int*   gcursor = chist + KC_MAX;                          // KC ints
    int*   offsets = gcursor + KC_MAX;                        // N+1 ints
    float* dinv    = (float*)(offsets + N + 1);               // N floats

    const int* srcp = ei;
    const int* dstp = ei + E;

    hipMemsetAsync(chist, 0, (size_t)KC_MAX * sizeof(int), stream);
    k_hist<<<(E + 4095) / 4096, 256, 0, stream>>>(dstp, chist, E);
    k_scanK<<<1, 64, 0, stream>>>(chist, gcursor, offsets, KC, N, E);

    int n_groups = (N + 15) / 16;
    k_gemm<<<1024, 256, 0, stream>>>(x, W, h, N, n_groups);

    k_part<<<(E + PTILE - 1) / PTILE, 256, 0, stream>>>(srcp, dstp, gcursor, part, E, KC);
    k_sort<<<KC, 256, 0, stream>>>(part, gcursor, part2, offsets, dinv, N);
    k_pull<<<(N * 64 + 255) / 256, 256, 0, stream>>>(offsets, part2, dinv, h, b, agg, N);

    k_spike<<<(N + 15) / 16, 256, 0, stream>>>(agg, o_seq, z_seq, N);
}